// Round 9
// baseline (241.288 us; speedup 1.0000x reference)
//
#include <hip/hip_runtime.h>
#include <hip/hip_bf16.h>

// Problem constants: N=20000 nodes, K=32 nbrs, C=128, H=256
#define NN    20000
#define KNN   32
#define CIN   128
#define HD    256
#define EE    (NN * KNN)        // 640000 edges
#define MT    64                // edge rows per tile = 2 full nodes
#define TPB   10                // tiles per block -> 20 nodes per block
#define NBLK  (EE / (MT * TPB)) // 1000 blocks
#define YSTR  264               // ldsY row stride (bf16), padded vs 256

typedef __bf16 bf16x8_t __attribute__((ext_vector_type(8)));
typedef __bf16 bf16x4_t __attribute__((ext_vector_type(4)));
typedef float  f32x4_t  __attribute__((ext_vector_type(4)));

// async global->LDS, 16B per lane; LDS dest = uniform base + lane*16
__device__ __forceinline__ void gload_lds16(const __bf16* g, __bf16* l) {
    __builtin_amdgcn_global_load_lds(
        (const __attribute__((address_space(1))) void*)g,
        (__attribute__((address_space(3))) void*)l, 16, 0, 0);
}

// Prep:
//  (a) nfb = bf16(nf)  (float4-vectorized)
//  (b) w1g = frag-ordered W1' where W1' = [W1a-W1b ; W1b]
//      w1g[((kt*4+qr)*256+n)*8+j] = W1'[k=kt*32+qr*8+j][n]
//      (h1 = x_v*(W1a-W1b) + x_vp*W1b; kt0-3 receiver half, kt4-7 sender half)
//  (c) w2t[n*256+k] = bf16(W2[k][n])
__global__ void ec_prep(const float* __restrict__ nf, const float* __restrict__ W1,
                        const float* __restrict__ W2, __bf16* __restrict__ nfb,
                        __bf16* __restrict__ w1g, __bf16* __restrict__ w2t) {
    int bid = blockIdx.x;
    if (bid < (NN * CIN) / 1024) {                  // 2500 blocks: nf cast
        int i = (bid * 256 + threadIdx.x) * 4;
        float4 v = *(const float4*)(nf + i);
        bf16x4_t b = { (__bf16)v.x, (__bf16)v.y, (__bf16)v.z, (__bf16)v.w };
        *(bf16x4_t*)(nfb + i) = b;
    } else {                                        // 256 blocks: weights
        int idx = (bid - (NN * CIN) / 1024) * 256 + threadIdx.x;   // 0..65535
        int k = idx >> 8, n = idx & 255;
        float v = (k < CIN) ? (W1[k * 256 + n] - W1[(k + CIN) * 256 + n])
                            : W1[k * 256 + n];
        int kt = k >> 5, qr = (k >> 3) & 3, j = k & 7;
        w1g[(size_t)((kt * 4 + qr) * 256 + n) * 8 + j] = (__bf16)v;
        w2t[n * 256 + k] = (__bf16)W2[k * 256 + n];
    }
}

// 512 thr / 8 waves, 1 block/CU.
// Once per block: Y = X_v(20 nodes) * W1A' -> ldsY (bf16, padded stride).
// Per tile: GEMM1 = acc(init Y) + x_vp*W1B' (kt4-5 regs, kt6-7 LDS, E from ldsE),
//           epi1 -> ldsH, GEMM2 = H(32e) x W2(64f, regs), max-reduce, store.
__global__ __launch_bounds__(512, 1) void ec_main(
    const __bf16* __restrict__ nfb,      // [NN][CIN] bf16
    const int*   __restrict__ senders,   // [EE]
    const __bf16* __restrict__ w1g,      // frag-ordered W1'
    const __bf16* __restrict__ w2t,      // [256 n][256 k]
    const float* __restrict__ b1,
    const float* __restrict__ b2,
    float* __restrict__ out)             // [NN][HD] fp32
{
    __shared__ __attribute__((aligned(16))) __bf16 ldsW[16384];    // 32 KB: W1B' kt6-7 frag-ordered
    __shared__ __attribute__((aligned(16))) __bf16 ldsE[2][8192];  // 2x16 KB: sender rows, frag-ordered
    __shared__ __attribute__((aligned(16))) __bf16 ldsH[16384];    // 32 KB: H, frag-ordered
    __shared__ __attribute__((aligned(16))) __bf16 ldsY[20 * YSTR];// ~10.3 KB: receiver partial (bf16)

    const int tid  = threadIdx.x;
    const int lane = tid & 63;
    const int wave = tid >> 6;           // 0..7
    const int qrow = lane >> 4;
    const int lcol = lane & 15;
    const int blk  = blockIdx.x;
    const int fsl  = wave * 32;          // GEMM1/epi1 feature slice
    const int fs2  = (wave >> 1) * 64;   // GEMM2 feature slice
    const int eh   = wave & 1;           // GEMM2 edge half (node within tile)
    // staging pair ids: pair p = kc*4 + quad
    const int p0 = wave * 2, p1 = wave * 2 + 1;
    const int c0 = p0 >> 2, q0 = p0 & 3;
    const int c1 = p1 >> 2, q1 = p1 & 3;

    // ---- copy W1B' kt6-7 (w1g chunks 24..31, 32 KB) into ldsW ----
    {
        const float4* src = (const float4*)(w1g + 49152);
        float4* dst = (float4*)ldsW;
#pragma unroll
        for (int i = 0; i < 4; ++i)
            dst[i * 512 + tid] = src[i * 512 + tid];
    }

    // ---- stage tile-0 sender rows into ldsE[0] (async) ----
    {
        int s0 = senders[blk * TPB * MT + lane];
        gload_lds16(nfb + (size_t)s0 * CIN + c0 * 32 + q0 * 8, &ldsE[0][p0 * 512]);
        gload_lds16(nfb + (size_t)s0 * CIN + c1 * 32 + q1 * 8, &ldsE[0][p1 * 512]);
    }

    // ---- once per block: Y = X_v * W1A' (swapped), store bf16 to ldsY ----
    {
        f32x4_t ay[2][2];
#pragma unroll
        for (int mi = 0; mi < 2; ++mi)
#pragma unroll
            for (int ni = 0; ni < 2; ++ni)
                ay[mi][ni] = (f32x4_t){0.f, 0.f, 0.f, 0.f};
        bf16x8_t xv[2][4];
#pragma unroll
        for (int ni = 0; ni < 2; ++ni) {
            int ln = ni * 16 + lcol; if (ln > 19) ln = 19;
            const __bf16* row = nfb + (size_t)(blk * 20 + ln) * CIN;
#pragma unroll
            for (int c = 0; c < 4; ++c)
                xv[ni][c] = *(const bf16x8_t*)(row + c * 32 + qrow * 8);
        }
#pragma unroll
        for (int kt = 0; kt < 4; ++kt) {
            bf16x8_t wy[2];
#pragma unroll
            for (int mi = 0; mi < 2; ++mi)
                wy[mi] = *(const bf16x8_t*)(w1g +
                    (size_t)((kt * 4 + qrow) * 256 + fsl + mi * 16 + lcol) * 8);
#pragma unroll
            for (int mi = 0; mi < 2; ++mi)
#pragma unroll
                for (int ni = 0; ni < 2; ++ni)
                    ay[mi][ni] = __builtin_amdgcn_mfma_f32_16x16x32_bf16(
                        wy[mi], xv[ni][kt], ay[mi][ni], 0, 0, 0);
        }
        // C-layout: row = feature fsl+mi*16+qrow*4+r, col = node ni*16+lcol
#pragma unroll
        for (int mi = 0; mi < 2; ++mi)
#pragma unroll
            for (int ni = 0; ni < 2; ++ni) {
                int ln = ni * 16 + lcol;
                if (ln < 20) {
                    bf16x4_t yb = { (__bf16)ay[mi][ni][0], (__bf16)ay[mi][ni][1],
                                    (__bf16)ay[mi][ni][2], (__bf16)ay[mi][ni][3] };
                    *(bf16x4_t*)(ldsY + ln * YSTR + fsl + mi * 16 + qrow * 4) = yb;
                }
            }
    }

    // ---- register-resident weights ----
    bf16x8_t w1s[2][2];                    // W1B' kt4-5 slice (32 VGPRs)
#pragma unroll
    for (int s = 0; s < 2; ++s)
#pragma unroll
        for (int mi = 0; mi < 2; ++mi)
            w1s[s][mi] = *(const bf16x8_t*)(w1g +
                (size_t)(((4 + s) * 4 + qrow) * 256 + fsl + mi * 16 + lcol) * 8);

    bf16x8_t w2f[8][4];                    // W2 64-feature slice (128 VGPRs)
#pragma unroll
    for (int kt = 0; kt < 8; ++kt)
#pragma unroll
        for (int ni = 0; ni < 4; ++ni)
            w2f[kt][ni] = *(const bf16x8_t*)(w2t + (size_t)(fs2 + ni * 16 + lcol) * 256
                                                 + kt * 32 + qrow * 8);

    float4 bias1[2];
#pragma unroll
    for (int mi = 0; mi < 2; ++mi)
        bias1[mi] = *(const float4*)(b1 + fsl + mi * 16 + qrow * 4);
    float bias2[4];
#pragma unroll
    for (int ni = 0; ni < 4; ++ni)
        bias2[ni] = b2[fs2 + ni * 16 + lcol];

    __syncthreads();   // ldsW + ldsE[0] (vmcnt drained) + ldsY ready

#pragma unroll 1
    for (int t = 0; t < TPB; ++t) {
        const int node0 = (blk * TPB + t) * 2;
        const int cur = t & 1;

        // ---- stage tile t+1 senders into the other ldsE buffer ----
        if (t + 1 < TPB) {
            int sN = senders[(blk * TPB + t + 1) * MT + lane];
            const __bf16* srow = nfb + (size_t)sN * CIN;
            gload_lds16(srow + c0 * 32 + q0 * 8, &ldsE[1 - cur][p0 * 512]);
            gload_lds16(srow + c1 * 32 + q1 * 8, &ldsE[1 - cur][p1 * 512]);
        }

        // ---- GEMM1: acc init from Y (bf16), + sender half ----
        f32x4_t acc[2][4];
#pragma unroll
        for (int mi = 0; mi < 2; ++mi)
#pragma unroll
            for (int ni = 0; ni < 4; ++ni) {
                bf16x4_t yb = *(const bf16x4_t*)(ldsY + (t * 2 + (ni >> 1)) * YSTR
                                                 + fsl + mi * 16 + qrow * 4);
                acc[mi][ni] = (f32x4_t){ (float)yb[0], (float)yb[1],
                                         (float)yb[2], (float)yb[3] };
            }
#pragma unroll
        for (int kt = 0; kt < 4; ++kt) {
            bf16x8_t wf[2], ef[4];
#pragma unroll
            for (int mi = 0; mi < 2; ++mi) {
                if (kt < 2) wf[mi] = w1s[kt][mi];
                else        wf[mi] = *(const bf16x8_t*)(ldsW +
                    (size_t)(((kt - 2) * 4 + qrow) * 256 + fsl + mi * 16 + lcol) * 8);
            }
#pragma unroll
            for (int ni = 0; ni < 4; ++ni)
                ef[ni] = *(const bf16x8_t*)(&ldsE[cur][0] +
                    (size_t)((kt * 4 + qrow) * 64 + ni * 16 + lcol) * 8);
#pragma unroll
            for (int mi = 0; mi < 2; ++mi)
#pragma unroll
                for (int ni = 0; ni < 4; ++ni)
                    acc[mi][ni] = __builtin_amdgcn_mfma_f32_16x16x32_bf16(
                        wf[mi], ef[ni], acc[mi][ni], 0, 0, 0);
        }

        __syncthreads();   // barrier A: ldsE[cur]/ldsH readers done; staging drained

        // ---- epilogue 1: +b1, relu, packed bf16x4 -> ldsH (frag-ordered) ----
#pragma unroll
        for (int mi = 0; mi < 2; ++mi) {
            const int f0  = fsl + mi * 16 + qrow * 4;
            const int ktp = f0 >> 5, qrp = (f0 >> 3) & 3, jh = f0 & 7;
            float4 bb = bias1[mi];
#pragma unroll
            for (int ni = 0; ni < 4; ++ni) {
                int edge = ni * 16 + lcol;
                float v0 = acc[mi][ni][0] + bb.x;
                float v1 = acc[mi][ni][1] + bb.y;
                float v2 = acc[mi][ni][2] + bb.z;
                float v3 = acc[mi][ni][3] + bb.w;
                bf16x4_t h = { (__bf16)fmaxf(v0, 0.f), (__bf16)fmaxf(v1, 0.f),
                               (__bf16)fmaxf(v2, 0.f), (__bf16)fmaxf(v3, 0.f) };
                *(bf16x4_t*)(ldsH + (size_t)((ktp * 4 + qrp) * 64 + edge) * 8 + jh) = h;
            }
        }
        __syncthreads();   // barrier B: ldsH ready

        // ---- GEMM2: D = H(32 edges) x W2(64 features, regs) ----
        f32x4_t acc2[2][4];
#pragma unroll
        for (int mi = 0; mi < 2; ++mi)
#pragma unroll
            for (int ni = 0; ni < 4; ++ni)
                acc2[mi][ni] = (f32x4_t){0.f, 0.f, 0.f, 0.f};
#pragma unroll
        for (int kt = 0; kt < 8; ++kt) {
            bf16x8_t af[2];
#pragma unroll
            for (int mi = 0; mi < 2; ++mi)
                af[mi] = *(const bf16x8_t*)(ldsH +
                    (size_t)((kt * 4 + qrow) * 64 + eh * 32 + mi * 16 + lcol) * 8);
#pragma unroll
            for (int mi = 0; mi < 2; ++mi)
#pragma unroll
                for (int ni = 0; ni < 4; ++ni)
                    acc2[mi][ni] = __builtin_amdgcn_mfma_f32_16x16x32_bf16(
                        af[mi], w2f[kt][ni], acc2[mi][ni], 0, 0, 0);
        }

        // ---- epilogue 2: max over this wave's node (32 edges), +b2, store ----
#pragma unroll
        for (int ni = 0; ni < 4; ++ni) {
            int col = fs2 + ni * 16 + lcol;
            float mx = -3.402823466e38f;
#pragma unroll
            for (int mi = 0; mi < 2; ++mi)
#pragma unroll
                for (int r = 0; r < 4; ++r)
                    mx = fmaxf(mx, acc2[mi][ni][r]);
            mx = fmaxf(mx, __shfl_xor(mx, 16, 64));
            mx = fmaxf(mx, __shfl_xor(mx, 32, 64));
            if (qrow == 0)
                out[(size_t)(node0 + eh) * HD + col] = mx + bias2[ni];
        }
    }
}

extern "C" void kernel_launch(void* const* d_in, const int* in_sizes, int n_in,
                              void* d_out, int out_size, void* d_ws, size_t ws_size,
                              hipStream_t stream) {
    const float* nf      = (const float*)d_in[0];
    const int*   senders = (const int*)d_in[1];
    // d_in[2] = receivers: implicit (repeat(arange(N), K)), unused
    const float* W1 = (const float*)d_in[3];
    const float* b1 = (const float*)d_in[4];
    const float* W2 = (const float*)d_in[5];
    const float* b2 = (const float*)d_in[6];

    __bf16* w1g = (__bf16*)d_ws;                 // 128 KB frag-ordered W1'
    __bf16* w2t = w1g + 256 * 256;               // 128 KB
    __bf16* nfb = w2t + 256 * 256;               // 5.12 MB bf16 node features

    ec_prep<<<(NN * CIN) / 1024 + 256, 256, 0, stream>>>(nf, W1, W2, nfb, w1g, w2t);
    ec_main<<<NBLK, 512, 0, stream>>>(nfb, senders, w1g, w2t, b1, b2, (float*)d_out);
}

// Round 10
// 230.125 us; speedup vs baseline: 1.0485x; 1.0485x over previous
//
#include <hip/hip_runtime.h>
#include <hip/hip_bf16.h>

// Problem constants: N=20000 nodes, K=32 nbrs, C=128, H=256
#define NN    20000
#define KNN   32
#define CIN   128
#define HD    256
#define EE    (NN * KNN)        // 640000 edges
#define MT    64                // edge rows per tile = 2 full nodes
#define TPB   10                // tiles per block -> 20 nodes per block
#define NBLK  (EE / (MT * TPB)) // 1000 blocks
#define YSTR  264               // ldsY row stride (bf16), padded

typedef __bf16 bf16x8_t __attribute__((ext_vector_type(8)));
typedef __bf16 bf16x4_t __attribute__((ext_vector_type(4)));
typedef float  f32x4_t  __attribute__((ext_vector_type(4)));

// async global->LDS, 16B per lane; LDS dest = uniform base + lane*16
__device__ __forceinline__ void gload_lds16(const __bf16* g, __bf16* l) {
    __builtin_amdgcn_global_load_lds(
        (const __attribute__((address_space(1))) void*)g,
        (__attribute__((address_space(3))) void*)l, 16, 0, 0);
}

// Prep:
//  (a) nfb = bf16(nf)
//  (b) w1g = frag-ordered W1' = [W1a-W1b ; W1b]:
//      w1g[((kt*4+qr)*256+n)*8+j] = W1'[k=kt*32+qr*8+j][n]
//  (c) w2g = frag-ordered W2 (same chunk layout)
__global__ void ec_prep(const float* __restrict__ nf, const float* __restrict__ W1,
                        const float* __restrict__ W2, __bf16* __restrict__ nfb,
                        __bf16* __restrict__ w1g, __bf16* __restrict__ w2g) {
    int bid = blockIdx.x;
    if (bid < (NN * CIN) / 1024) {                  // 2500 blocks: nf cast
        int i = (bid * 256 + threadIdx.x) * 4;
        float4 v = *(const float4*)(nf + i);
        bf16x4_t b = { (__bf16)v.x, (__bf16)v.y, (__bf16)v.z, (__bf16)v.w };
        *(bf16x4_t*)(nfb + i) = b;
    } else {                                        // 256 blocks: weights
        int idx = (bid - (NN * CIN) / 1024) * 256 + threadIdx.x;   // 0..65535
        int k = idx >> 8, n = idx & 255;
        float v1 = (k < CIN) ? (W1[k * 256 + n] - W1[(k + CIN) * 256 + n])
                             : W1[k * 256 + n];
        int kt = k >> 5, qr = (k >> 3) & 3, j = k & 7;
        size_t off = (size_t)((kt * 4 + qr) * 256 + n) * 8 + j;
        w1g[off] = (__bf16)v1;
        w2g[off] = (__bf16)W2[k * 256 + n];
    }
}

// 512 thr / 8 waves, 1 block/CU. Pinned-register weights (W2 kt0-6, W1B' kt0-1),
// small LDS for the rest; double-buffered ldsE (DMA-staged) and ldsH
// (cross-tile pipelined GEMM2) -> ONE barrier per tile.
__global__ __launch_bounds__(512, 2) void ec_main(
    const __bf16* __restrict__ nfb,      // [NN][CIN] bf16
    const int*   __restrict__ senders,   // [EE]
    const __bf16* __restrict__ w1g,      // frag-ordered W1'
    const __bf16* __restrict__ w2g,      // frag-ordered W2
    const float* __restrict__ b1,
    const float* __restrict__ b2,
    float* __restrict__ out)             // [NN][HD] fp32
{
    __shared__ __attribute__((aligned(16))) __bf16 ldsW1s[16384];   // 32 KB: W1B' kt2-3 (chunks 24..31)
    __shared__ __attribute__((aligned(16))) __bf16 ldsW27[8192];    // 16 KB: W2 kt7   (chunks 28..31)
    __shared__ __attribute__((aligned(16))) __bf16 ldsE[2][8192];   // 32 KB: sender rows, frag-ordered
    __shared__ __attribute__((aligned(16))) __bf16 ldsH[2][16384];  // 64 KB: H double-buffered
    __shared__ __attribute__((aligned(16))) __bf16 ldsY[20 * YSTR]; // 10.3 KB: receiver partial

    const int tid  = threadIdx.x;
    const int lane = tid & 63;
    const int wave = tid >> 6;           // 0..7
    const int qrow = lane >> 4;
    const int lcol = lane & 15;
    const int blk  = blockIdx.x;
    const int fsl  = wave * 32;          // GEMM1/epi1 feature slice
    const int fs2  = (wave >> 1) * 64;   // GEMM2 feature slice
    const int eh   = wave & 1;           // GEMM2 node within tile
    const int p0 = wave * 2, p1 = wave * 2 + 1;        // staging pairs
    const int c0 = p0 >> 2, q0 = p0 & 3;
    const int c1 = p1 >> 2, q1 = p1 & 3;

    // ---- LDS weight copies ----
    {
        const float4* s1 = (const float4*)(w1g + 49152);   // chunks 24..31
        float4* d1 = (float4*)ldsW1s;
#pragma unroll
        for (int i = 0; i < 4; ++i) d1[i * 512 + tid] = s1[i * 512 + tid];
        const float4* s2 = (const float4*)(w2g + 57344);   // chunks 28..31
        float4* d2 = (float4*)ldsW27;
#pragma unroll
        for (int i = 0; i < 2; ++i) d2[i * 512 + tid] = s2[i * 512 + tid];
    }

    // ---- stage tile-0 sender rows into ldsE[0] (async DMA) ----
    {
        int s0 = senders[blk * TPB * MT + lane];
        gload_lds16(nfb + (size_t)s0 * CIN + c0 * 32 + q0 * 8, &ldsE[0][p0 * 512]);
        gload_lds16(nfb + (size_t)s0 * CIN + c1 * 32 + q1 * 8, &ldsE[0][p1 * 512]);
    }

    // ---- once per block: Y = X_v(20 nodes) * W1A' -> ldsY (bf16, padded) ----
    {
        f32x4_t ay[2][2];
#pragma unroll
        for (int mi = 0; mi < 2; ++mi)
#pragma unroll
            for (int ni = 0; ni < 2; ++ni)
                ay[mi][ni] = (f32x4_t){0.f, 0.f, 0.f, 0.f};
        bf16x8_t xv[2][4];
#pragma unroll
        for (int ni = 0; ni < 2; ++ni) {
            int ln = ni * 16 + lcol; if (ln > 19) ln = 19;
            const __bf16* row = nfb + (size_t)(blk * 20 + ln) * CIN;
#pragma unroll
            for (int c = 0; c < 4; ++c)
                xv[ni][c] = *(const bf16x8_t*)(row + c * 32 + qrow * 8);
        }
#pragma unroll
        for (int kt = 0; kt < 4; ++kt) {
            bf16x8_t wy[2];
#pragma unroll
            for (int mi = 0; mi < 2; ++mi)
                wy[mi] = *(const bf16x8_t*)(w1g +
                    (size_t)((kt * 4 + qrow) * 256 + fsl + mi * 16 + lcol) * 8);
#pragma unroll
            for (int mi = 0; mi < 2; ++mi)
#pragma unroll
                for (int ni = 0; ni < 2; ++ni)
                    ay[mi][ni] = __builtin_amdgcn_mfma_f32_16x16x32_bf16(
                        wy[mi], xv[ni][kt], ay[mi][ni], 0, 0, 0);
        }
#pragma unroll
        for (int mi = 0; mi < 2; ++mi)
#pragma unroll
            for (int ni = 0; ni < 2; ++ni) {
                int ln = ni * 16 + lcol;
                if (ln < 20) {
                    bf16x4_t yb = { (__bf16)ay[mi][ni][0], (__bf16)ay[mi][ni][1],
                                    (__bf16)ay[mi][ni][2], (__bf16)ay[mi][ni][3] };
                    *(bf16x4_t*)(ldsY + ln * YSTR + fsl + mi * 16 + qrow * 4) = yb;
                }
            }
    }

    // ---- register-resident weights, PINNED so the RA cannot rematerialize ----
    bf16x8_t w1s[2][2];                    // W1B' kt0-1 (32 VGPRs)
#pragma unroll
    for (int s = 0; s < 2; ++s)
#pragma unroll
        for (int mi = 0; mi < 2; ++mi)
            w1s[s][mi] = *(const bf16x8_t*)(w1g +
                (size_t)(((4 + s) * 4 + qrow) * 256 + fsl + mi * 16 + lcol) * 8);

    bf16x8_t w2f[7][4];                    // W2 kt0-6 slice (112 VGPRs)
#pragma unroll
    for (int kt = 0; kt < 7; ++kt)
#pragma unroll
        for (int ni = 0; ni < 4; ++ni)
            w2f[kt][ni] = *(const bf16x8_t*)(w2g +
                (size_t)((kt * 4 + qrow) * 256 + fs2 + ni * 16 + lcol) * 8);

#pragma unroll
    for (int s = 0; s < 2; ++s)
#pragma unroll
        for (int mi = 0; mi < 2; ++mi)
            asm volatile("" : "+v"(w1s[s][mi]));
#pragma unroll
    for (int kt = 0; kt < 7; ++kt)
#pragma unroll
        for (int ni = 0; ni < 4; ++ni)
            asm volatile("" : "+v"(w2f[kt][ni]));

    float4 bias1[2];
#pragma unroll
    for (int mi = 0; mi < 2; ++mi)
        bias1[mi] = *(const float4*)(b1 + fsl + mi * 16 + qrow * 4);
    float bias2[4];
#pragma unroll
    for (int ni = 0; ni < 4; ++ni)
        bias2[ni] = b2[fs2 + ni * 16 + lcol];

    __syncthreads();   // init LDS (W copies, E[0] DMA, Y) ready

#pragma unroll 1
    for (int t = 0; t <= TPB; ++t) {
        const int cur = t & 1;
        f32x4_t acc[2][4];

        if (t < TPB) {
            // ---- stage tile t+1 senders into the other ldsE buffer (drains at the
            //      barrier below, fully covered by GEMM1) ----
            if (t + 1 < TPB) {
                int sN = senders[(blk * TPB + t + 1) * MT + lane];
                const __bf16* srow = nfb + (size_t)sN * CIN;
                gload_lds16(srow + c0 * 32 + q0 * 8, &ldsE[1 - cur][p0 * 512]);
                gload_lds16(srow + c1 * 32 + q1 * 8, &ldsE[1 - cur][p1 * 512]);
            }

            // ---- GEMM1: acc init from Y, + sender half (kt0-1 regs, kt2-3 LDS) ----
#pragma unroll
            for (int mi = 0; mi < 2; ++mi)
#pragma unroll
                for (int ni = 0; ni < 4; ++ni) {
                    bf16x4_t yb = *(const bf16x4_t*)(ldsY + (t * 2 + (ni >> 1)) * YSTR
                                                     + fsl + mi * 16 + qrow * 4);
                    acc[mi][ni] = (f32x4_t){ (float)yb[0], (float)yb[1],
                                             (float)yb[2], (float)yb[3] };
                }
#pragma unroll
            for (int kt = 0; kt < 4; ++kt) {
                bf16x8_t wf[2], ef[4];
#pragma unroll
                for (int mi = 0; mi < 2; ++mi) {
                    if (kt < 2) wf[mi] = w1s[kt][mi];
                    else        wf[mi] = *(const bf16x8_t*)(ldsW1s +
                        (size_t)(((kt - 2) * 4 + qrow) * 256 + fsl + mi * 16 + lcol) * 8);
                }
#pragma unroll
                for (int ni = 0; ni < 4; ++ni)
                    ef[ni] = *(const bf16x8_t*)(&ldsE[cur][0] +
                        (size_t)((kt * 4 + qrow) * 64 + ni * 16 + lcol) * 8);
#pragma unroll
                for (int mi = 0; mi < 2; ++mi)
#pragma unroll
                    for (int ni = 0; ni < 4; ++ni)
                        acc[mi][ni] = __builtin_amdgcn_mfma_f32_16x16x32_bf16(
                            wf[mi], ef[ni], acc[mi][ni], 0, 0, 0);
            }
        }

        __syncthreads();   // the ONE barrier: E-DMA drained, H(t-1) visible,
                           // E[cur]/H[cur] readers from previous iteration done

        if (t < TPB) {
            // ---- epilogue 1: +b1, relu, packed bf16x4 -> ldsH[cur] ----
#pragma unroll
            for (int mi = 0; mi < 2; ++mi) {
                const int f0  = fsl + mi * 16 + qrow * 4;
                const int ktp = f0 >> 5, qrp = (f0 >> 3) & 3, jh = f0 & 7;
                float4 bb = bias1[mi];
#pragma unroll
                for (int ni = 0; ni < 4; ++ni) {
                    int edge = ni * 16 + lcol;
                    float v0 = acc[mi][ni][0] + bb.x;
                    float v1 = acc[mi][ni][1] + bb.y;
                    float v2 = acc[mi][ni][2] + bb.z;
                    float v3 = acc[mi][ni][3] + bb.w;
                    bf16x4_t h = { (__bf16)fmaxf(v0, 0.f), (__bf16)fmaxf(v1, 0.f),
                                   (__bf16)fmaxf(v2, 0.f), (__bf16)fmaxf(v3, 0.f) };
                    *(bf16x4_t*)(&ldsH[cur][0] +
                        (size_t)((ktp * 4 + qrp) * 64 + edge) * 8 + jh) = h;
                }
            }
        }

        if (t > 0) {
            // ---- GEMM2 for tile t-1: D = H(32 edges) x W2 (kt0-6 regs, kt7 LDS) ----
            const __bf16* Hp = &ldsH[1 - cur][0];
            f32x4_t acc2[2][4];
#pragma unroll
            for (int mi = 0; mi < 2; ++mi)
#pragma unroll
                for (int ni = 0; ni < 4; ++ni)
                    acc2[mi][ni] = (f32x4_t){0.f, 0.f, 0.f, 0.f};
#pragma unroll
            for (int kt = 0; kt < 8; ++kt) {
                bf16x8_t af[2], wf[4];
#pragma unroll
                for (int mi = 0; mi < 2; ++mi)
                    af[mi] = *(const bf16x8_t*)(Hp +
                        (size_t)((kt * 4 + qrow) * 64 + eh * 32 + mi * 16 + lcol) * 8);
#pragma unroll
                for (int ni = 0; ni < 4; ++ni) {
                    if (kt < 7) wf[ni] = w2f[kt][ni];
                    else        wf[ni] = *(const bf16x8_t*)(ldsW27 +
                        (size_t)(qrow * 256 + fs2 + ni * 16 + lcol) * 8);
                }
#pragma unroll
                for (int mi = 0; mi < 2; ++mi)
#pragma unroll
                    for (int ni = 0; ni < 4; ++ni)
                        acc2[mi][ni] = __builtin_amdgcn_mfma_f32_16x16x32_bf16(
                            af[mi], wf[ni], acc2[mi][ni], 0, 0, 0);
            }

            // ---- epilogue 2: max over this wave's node, +b2, store (tile t-1) ----
            const int node0p = (blk * TPB + t - 1) * 2;
#pragma unroll
            for (int ni = 0; ni < 4; ++ni) {
                int col = fs2 + ni * 16 + lcol;
                float mx = -3.402823466e38f;
#pragma unroll
                for (int mi = 0; mi < 2; ++mi)
#pragma unroll
                    for (int r = 0; r < 4; ++r)
                        mx = fmaxf(mx, acc2[mi][ni][r]);
                mx = fmaxf(mx, __shfl_xor(mx, 16, 64));
                mx = fmaxf(mx, __shfl_xor(mx, 32, 64));
                if (qrow == 0)
                    out[(size_t)(node0p + eh) * HD + col] = mx + bias2[ni];
            }
        }
    }
}

extern "C" void kernel_launch(void* const* d_in, const int* in_sizes, int n_in,
                              void* d_out, int out_size, void* d_ws, size_t ws_size,
                              hipStream_t stream) {
    const float* nf      = (const float*)d_in[0];
    const int*   senders = (const int*)d_in[1];
    // d_in[2] = receivers: implicit (repeat(arange(N), K)), unused
    const float* W1 = (const float*)d_in[3];
    const float* b1 = (const float*)d_in[4];
    const float* W2 = (const float*)d_in[5];
    const float* b2 = (const float*)d_in[6];

    __bf16* w1g = (__bf16*)d_ws;                 // 128 KB frag-ordered W1'
    __bf16* w2g = w1g + 256 * 256;               // 128 KB frag-ordered W2
    __bf16* nfb = w2g + 256 * 256;               // 5.12 MB bf16 node features

    ec_prep<<<(NN * CIN) / 1024 + 256, 256, 0, stream>>>(nf, W1, W2, nfb, w1g, w2g);
    ec_main<<<NBLK, 512, 0, stream>>>(nfb, senders, w1g, w2g, b1, b2, (float*)d_out);
}